// Round 1
// baseline (1952.720 us; speedup 1.0000x reference)
//
#include <hip/hip_runtime.h>

#define N_NODES 100000
#define N_EDGES 1600000
#define IN_DIM 128
#define HIDDEN 256
#define EMBED 64
#define K_STEPS 10

// ---------------- fused MLP: h0 = relu(x@W1+b1)@W2 + b2 ----------------
__global__ __launch_bounds__(256) void mlp_fused(
    const float* __restrict__ x, const float* __restrict__ W1, const float* __restrict__ b1,
    const float* __restrict__ W2, const float* __restrict__ b2, float* __restrict__ h0, int n)
{
    __shared__ float Xs[32][128];     // 16 KB
    __shared__ float H1s[32][257];    // ~32 KB, stride 257 kills bank conflicts in phase 2
    int t = threadIdx.x;
    int rowBase = blockIdx.x * 32;

    // load X tile (32 x 128) as float4, fully coalesced
    {
        const float4* x4 = (const float4*)(x + (size_t)rowBase * IN_DIM);
        float4* xs4 = (float4*)(&Xs[0][0]);
        #pragma unroll
        for (int i = t; i < 32 * (IN_DIM / 4); i += 256) xs4[i] = x4[i];
    }
    __syncthreads();

    // ---- phase 1: H1 = relu(X @ W1 + b1), tile 32x256 ----
    int ty = t >> 6;   // wave id 0..3 (uniform per wave -> Xs reads broadcast)
    int tx = t & 63;   // lane
    float acc[8][4];
    #pragma unroll
    for (int rr = 0; rr < 8; ++rr)
        #pragma unroll
        for (int cc = 0; cc < 4; ++cc) acc[rr][cc] = b1[tx + 64 * cc];

    #pragma unroll 4
    for (int k = 0; k < IN_DIM; ++k) {
        float wv[4];
        #pragma unroll
        for (int cc = 0; cc < 4; ++cc) wv[cc] = W1[k * HIDDEN + tx + 64 * cc];
        #pragma unroll
        for (int rr = 0; rr < 8; ++rr) {
            float xv = Xs[ty + 4 * rr][k];
            #pragma unroll
            for (int cc = 0; cc < 4; ++cc) acc[rr][cc] += xv * wv[cc];
        }
    }
    #pragma unroll
    for (int rr = 0; rr < 8; ++rr)
        #pragma unroll
        for (int cc = 0; cc < 4; ++cc)
            H1s[ty + 4 * rr][tx + 64 * cc] = fmaxf(acc[rr][cc], 0.0f);
    __syncthreads();

    // ---- phase 2: H0 = H1 @ W2 + b2, tile 32x64 ----
    int cx = t & 7;    // col group: cols cx*8 .. cx*8+7
    int ry = t >> 3;   // row 0..31
    float acc2[8];
    #pragma unroll
    for (int j = 0; j < 8; ++j) acc2[j] = b2[cx * 8 + j];

    #pragma unroll 4
    for (int k = 0; k < HIDDEN; ++k) {
        float hv = H1s[ry][k];
        float4 wa = *(const float4*)(W2 + k * EMBED + cx * 8);
        float4 wb = *(const float4*)(W2 + k * EMBED + cx * 8 + 4);
        acc2[0] += hv * wa.x; acc2[1] += hv * wa.y; acc2[2] += hv * wa.z; acc2[3] += hv * wa.w;
        acc2[4] += hv * wb.x; acc2[5] += hv * wb.y; acc2[6] += hv * wb.z; acc2[7] += hv * wb.w;
    }
    int r = rowBase + ry;
    if (r < n) {
        float4* o4 = (float4*)(h0 + (size_t)r * EMBED + cx * 8);
        o4[0] = make_float4(acc2[0], acc2[1], acc2[2], acc2[3]);
        o4[1] = make_float4(acc2[4], acc2[5], acc2[6], acc2[7]);
    }
}

// ---------------- graph prep ----------------
__global__ void zero_int(int* p, int n) {
    int i = blockIdx.x * 256 + threadIdx.x; if (i < n) p[i] = 0;
}
__global__ void count_deg(const int* __restrict__ col, int* __restrict__ cnt, int e) {
    int i = blockIdx.x * 256 + threadIdx.x; if (i < e) atomicAdd(&cnt[col[i]], 1);
}
__global__ void calc_dinv(const int* __restrict__ cnt, float* __restrict__ dinv, int n) {
    int i = blockIdx.x * 256 + threadIdx.x;
    if (i < n) dinv[i] = rsqrtf((float)(cnt[i] + 1));  // +1 self-loop; always > 0
}
__global__ void block_reduce(const int* __restrict__ cnt, int* __restrict__ bsum, int n) {
    __shared__ int sh[256];
    int i = blockIdx.x * 256 + threadIdx.x;
    sh[threadIdx.x] = (i < n) ? cnt[i] : 0; __syncthreads();
    for (int o = 128; o > 0; o >>= 1) {
        if (threadIdx.x < o) sh[threadIdx.x] += sh[threadIdx.x + o];
        __syncthreads();
    }
    if (threadIdx.x == 0) bsum[blockIdx.x] = sh[0];
}
__global__ void scan_bsum(int* bsum, int nb) {
    if (threadIdx.x == 0) {
        int run = 0;
        for (int b = 0; b < nb; ++b) { int tmp = bsum[b]; bsum[b] = run; run += tmp; }
    }
}
__global__ void block_scan(int* __restrict__ cnt, const int* __restrict__ bsum,
                           int* __restrict__ off, int n) {
    __shared__ int sh[256];
    int t = threadIdx.x, i = blockIdx.x * 256 + t;
    int v = (i < n) ? cnt[i] : 0;
    sh[t] = v; __syncthreads();
    for (int o = 1; o < 256; o <<= 1) {
        int a = (t >= o) ? sh[t - o] : 0;
        __syncthreads();
        sh[t] += a;
        __syncthreads();
    }
    if (i < n) { off[i] = bsum[blockIdx.x] + sh[t] - v; cnt[i] = 0; }  // cnt reused as cursor
}
__global__ void set_tail(int* off) { off[N_NODES] = N_EDGES; }

__global__ void fill_csc(const int* __restrict__ row, const int* __restrict__ col,
                         const int* __restrict__ off, int* __restrict__ cur,
                         const float* __restrict__ dinv, int2* __restrict__ ew, int e) {
    int i = blockIdx.x * 256 + threadIdx.x;
    if (i >= e) return;
    int c = col[i], r = row[i];
    int p = off[c] + atomicAdd(&cur[c], 1);
    ew[p] = make_int2(r, __float_as_int(dinv[r] * dinv[c]));
}

// ---------------- propagation: pull over CSC, one lane per (node, dim) ----------------
__global__ __launch_bounds__(256) void prop_kernel(
    const int* __restrict__ off, const int2* __restrict__ ew,
    const float* __restrict__ hin, const float* __restrict__ x0,
    const float* __restrict__ dinv, float* __restrict__ hout, int n)
{
    int t = threadIdx.x;
    int v = blockIdx.x * 4 + (t >> 6);   // 4 nodes per block, 64 lanes per node
    int d = t & 63;
    if (v >= n) return;
    float dv = dinv[v];
    float acc = dv * dv * hin[v * 64 + d];       // self-loop
    int s = off[v], e = off[v + 1];
    for (int i = s; i < e; ++i) {
        int2 p = ew[i];
        acc += __int_as_float(p.y) * hin[p.x * 64 + d];
    }
    hout[v * 64 + d] = 0.9f * acc + 0.1f * x0[v * 64 + d];
}

extern "C" void kernel_launch(void* const* d_in, const int* in_sizes, int n_in,
                              void* d_out, int out_size, void* d_ws, size_t ws_size,
                              hipStream_t stream)
{
    const float* x  = (const float*)d_in[0];
    const int*   ei = (const int*)d_in[1];
    const float* W1 = (const float*)d_in[2];
    const float* b1 = (const float*)d_in[3];
    const float* W2 = (const float*)d_in[4];
    const float* b2 = (const float*)d_in[5];
    float* out = (float*)d_out;
    const int* row = ei;             // edge_index[0]
    const int* col = ei + N_EDGES;   // edge_index[1]

    // workspace carve-out (~65 MB)
    char* w = (char*)d_ws;
    float* h0   = (float*)w; w += (size_t)N_NODES * EMBED * 4;   // x0 / MLP output
    float* hA   = (float*)w; w += (size_t)N_NODES * EMBED * 4;   // odd-step buffer
    int*   cnt  = (int*)w;   w += (size_t)N_NODES * 4;           // counts, then cursor
    int*   off  = (int*)w;   w += (size_t)(N_NODES + 1) * 4 + 12;
    int*   bsum = (int*)w;   w += 4096;
    float* dinv = (float*)w; w += (size_t)N_NODES * 4;
    int2*  ew   = (int2*)w;  w += (size_t)N_EDGES * 8;

    int nbN = (N_NODES + 255) / 256;
    int nbE = (N_EDGES + 255) / 256;

    mlp_fused<<<(N_NODES + 31) / 32, 256, 0, stream>>>(x, W1, b1, W2, b2, h0, N_NODES);

    zero_int<<<nbN, 256, 0, stream>>>(cnt, N_NODES);
    count_deg<<<nbE, 256, 0, stream>>>(col, cnt, N_EDGES);
    calc_dinv<<<nbN, 256, 0, stream>>>(cnt, dinv, N_NODES);
    block_reduce<<<nbN, 256, 0, stream>>>(cnt, bsum, N_NODES);
    scan_bsum<<<1, 64, 0, stream>>>(bsum, nbN);
    block_scan<<<nbN, 256, 0, stream>>>(cnt, bsum, off, N_NODES);
    set_tail<<<1, 1, 0, stream>>>(off);
    fill_csc<<<nbE, 256, 0, stream>>>(row, col, off, cnt, dinv, ew, N_EDGES);

    // K=10 propagation steps; even steps (s odd) write d_out so step 10 lands in d_out
    const float* hin = h0;
    for (int s = 0; s < K_STEPS; ++s) {
        float* hout = (s & 1) ? out : hA;
        prop_kernel<<<N_NODES / 4, 256, 0, stream>>>(off, ew, hin, h0, dinv, hout, N_NODES);
        hin = hout;
    }
}

// Round 2
// 696.498 us; speedup vs baseline: 2.8036x; 2.8036x over previous
//
#include <hip/hip_runtime.h>

#define N_NODES 100000
#define N_EDGES 1600000
#define IN_DIM 128
#define HIDDEN 256
#define EMBED 64
#define K_STEPS 10

typedef unsigned int u32;
using bf16x8 = __attribute__((ext_vector_type(8))) short;
using f32x4  = __attribute__((ext_vector_type(4))) float;

__device__ __forceinline__ float bflo(u32 u) { return __uint_as_float(u << 16); }
__device__ __forceinline__ float bfhi(u32 u) { return __uint_as_float(u & 0xffff0000u); }
__device__ __forceinline__ unsigned short f2bf(float f) {   // round-to-nearest-even
    u32 u = __float_as_uint(f);
    u += 0x7fffu + ((u >> 16) & 1u);
    return (unsigned short)(u >> 16);
}

// ---------------- weight prep: transpose + bf16 convert ----------------
// W1T[n][k] = bf16(W1[k][n])  (256 x 128), W2T[n][k] = bf16(W2[k][n]) (64 x 256)
__global__ void conv_weights(const float* __restrict__ W1, const float* __restrict__ W2,
                             unsigned short* __restrict__ W1T, unsigned short* __restrict__ W2T)
{
    int i = blockIdx.x * 256 + threadIdx.x;
    if (i < IN_DIM * HIDDEN) {
        int n = i / IN_DIM, k = i % IN_DIM;
        W1T[i] = f2bf(W1[k * HIDDEN + n]);
    }
    int j = i - IN_DIM * HIDDEN;
    if (j >= 0 && j < HIDDEN * EMBED) {
        int n = j / HIDDEN, k = j % HIDDEN;
        W2T[j] = f2bf(W2[k * EMBED + n]);
    }
}

// ---------------- fused MLP via bf16 MFMA ----------------
// block = 256 thr (4 waves), 64 rows per block.
// phase 1: H1[64][256] = relu(X@W1+b1), wave w owns cols w*64..+63
// phase 2: H0[64][64]  = H1@W2+b2,      wave w owns rows w*16..+15
__global__ __launch_bounds__(256) void mlp_mfma(
    const float* __restrict__ x, const unsigned short* __restrict__ W1T,
    const float* __restrict__ b1, const unsigned short* __restrict__ W2T,
    const float* __restrict__ b2, unsigned short* __restrict__ h0bf, int n)
{
    __shared__ unsigned short Xs[64][136];    // +8 pad: row stride 272B (17*16) -> 2-way banks, 16B aligned
    __shared__ unsigned short H1s[64][264];   // +8 pad: row stride 528B (33*16)
    int t = threadIdx.x;
    int rowBase = blockIdx.x * 64;
    int lane = t & 63, w = t >> 6;
    int lr = lane & 15, kg = lane >> 4;

    // stage X tile (64x128 fp32 -> bf16 LDS), coalesced float4
    for (int i = t; i < 64 * 32; i += 256) {
        int row = i >> 5, c4 = (i & 31) * 4;
        float4 v = make_float4(0.f, 0.f, 0.f, 0.f);
        if (rowBase + row < n) v = *(const float4*)(x + (size_t)(rowBase + row) * IN_DIM + c4);
        Xs[row][c4 + 0] = f2bf(v.x); Xs[row][c4 + 1] = f2bf(v.y);
        Xs[row][c4 + 2] = f2bf(v.z); Xs[row][c4 + 3] = f2bf(v.w);
    }
    __syncthreads();

    // ---- phase 1 ----
    {
        int n0 = w * 64;
        f32x4 acc[4][4];
        #pragma unroll
        for (int m = 0; m < 4; ++m)
            #pragma unroll
            for (int nn = 0; nn < 4; ++nn) acc[m][nn] = (f32x4){0.f, 0.f, 0.f, 0.f};

        #pragma unroll
        for (int k0 = 0; k0 < IN_DIM; k0 += 32) {
            bf16x8 a[4], b[4];
            #pragma unroll
            for (int m = 0; m < 4; ++m)
                a[m] = *(const bf16x8*)&Xs[m * 16 + lr][k0 + kg * 8];
            #pragma unroll
            for (int nn = 0; nn < 4; ++nn)
                b[nn] = *(const bf16x8*)(W1T + (size_t)(n0 + nn * 16 + lr) * IN_DIM + k0 + kg * 8);
            #pragma unroll
            for (int m = 0; m < 4; ++m)
                #pragma unroll
                for (int nn = 0; nn < 4; ++nn)
                    acc[m][nn] = __builtin_amdgcn_mfma_f32_16x16x32_bf16(a[m], b[nn], acc[m][nn], 0, 0, 0);
        }
        // D layout: col = lane&15, row = (lane>>4)*4 + reg  [m89-verified]
        #pragma unroll
        for (int nn = 0; nn < 4; ++nn) {
            float bb = b1[n0 + nn * 16 + lr];
            #pragma unroll
            for (int m = 0; m < 4; ++m)
                #pragma unroll
                for (int r = 0; r < 4; ++r)
                    H1s[m * 16 + kg * 4 + r][n0 + nn * 16 + lr] =
                        f2bf(fmaxf(acc[m][nn][r] + bb, 0.f));
        }
    }
    __syncthreads();

    // ---- phase 2 ----
    {
        int r0 = w * 16;
        f32x4 acc[4];
        #pragma unroll
        for (int nn = 0; nn < 4; ++nn) acc[nn] = (f32x4){0.f, 0.f, 0.f, 0.f};

        #pragma unroll
        for (int k0 = 0; k0 < HIDDEN; k0 += 32) {
            bf16x8 a = *(const bf16x8*)&H1s[r0 + lr][k0 + kg * 8];
            #pragma unroll
            for (int nn = 0; nn < 4; ++nn) {
                bf16x8 b = *(const bf16x8*)(W2T + (size_t)(nn * 16 + lr) * HIDDEN + k0 + kg * 8);
                acc[nn] = __builtin_amdgcn_mfma_f32_16x16x32_bf16(a, b, acc[nn], 0, 0, 0);
            }
        }
        #pragma unroll
        for (int nn = 0; nn < 4; ++nn) {
            float bb = b2[nn * 16 + lr];
            #pragma unroll
            for (int r = 0; r < 4; ++r) {
                int row = rowBase + r0 + kg * 4 + r;
                if (row < n)
                    h0bf[(size_t)row * EMBED + nn * 16 + lr] = f2bf(acc[nn][r] + bb);
            }
        }
    }
}

// ---------------- graph prep ----------------
__global__ void zero_int(int* p, int n) {
    int i = blockIdx.x * 256 + threadIdx.x; if (i < n) p[i] = 0;
}
__global__ void count_deg(const int* __restrict__ col, int* __restrict__ cnt, int e) {
    int i = blockIdx.x * 256 + threadIdx.x; if (i < e) atomicAdd(&cnt[col[i]], 1);
}
__global__ void calc_dinv(const int* __restrict__ cnt, float* __restrict__ dinv, int n) {
    int i = blockIdx.x * 256 + threadIdx.x;
    if (i < n) dinv[i] = rsqrtf((float)(cnt[i] + 1));
}
__global__ void block_reduce(const int* __restrict__ cnt, int* __restrict__ bsum, int n) {
    __shared__ int sh[256];
    int i = blockIdx.x * 256 + threadIdx.x;
    sh[threadIdx.x] = (i < n) ? cnt[i] : 0; __syncthreads();
    for (int o = 128; o > 0; o >>= 1) {
        if (threadIdx.x < o) sh[threadIdx.x] += sh[threadIdx.x + o];
        __syncthreads();
    }
    if (threadIdx.x == 0) bsum[blockIdx.x] = sh[0];
}
__global__ void scan_bsum(int* bsum, int nb) {
    if (threadIdx.x == 0) {
        int run = 0;
        for (int b = 0; b < nb; ++b) { int tmp = bsum[b]; bsum[b] = run; run += tmp; }
    }
}
__global__ void block_scan(int* __restrict__ cnt, const int* __restrict__ bsum,
                           int* __restrict__ off, int n) {
    __shared__ int sh[256];
    int t = threadIdx.x, i = blockIdx.x * 256 + t;
    int v = (i < n) ? cnt[i] : 0;
    sh[t] = v; __syncthreads();
    for (int o = 1; o < 256; o <<= 1) {
        int a = (t >= o) ? sh[t - o] : 0;
        __syncthreads();
        sh[t] += a;
        __syncthreads();
    }
    if (i < n) { off[i] = bsum[blockIdx.x] + sh[t] - v; cnt[i] = 0; }  // cnt reused as cursor
}
__global__ void set_tail(int* off) { off[N_NODES] = N_EDGES; }

__global__ void fill_csc(const int* __restrict__ row, const int* __restrict__ col,
                         const int* __restrict__ off, int* __restrict__ cur,
                         const float* __restrict__ dinv, int2* __restrict__ ew, int e) {
    int i = blockIdx.x * 256 + threadIdx.x;
    if (i >= e) return;
    int c = col[i], r = row[i];
    int p = off[c] + atomicAdd(&cur[c], 1);
    ew[p] = make_int2(r, __float_as_int(dinv[r] * dinv[c]));
}

// ---------------- propagation: pull over CSC, bf16 h, fp32 accumulate ----------------
// 32 lanes per node (2 dims/lane), 8 nodes per 256-thr block; edge loop unrolled x4
// with independent accumulators so 4 gathers are in flight per half-wave.
__global__ __launch_bounds__(256) void prop_bf16(
    const int* __restrict__ off, const int2* __restrict__ ew,
    const unsigned short* __restrict__ hin, const unsigned short* __restrict__ x0,
    const float* __restrict__ dinv, unsigned short* __restrict__ hob,
    float* __restrict__ hof, int final_step)
{
    int t = threadIdx.x;
    int v = blockIdx.x * 8 + (t >> 5);        // grid is exact: 12500*8 = 100000
    int d2 = (t & 31) * 2;
    int s = off[v], e = off[v + 1];
    float a0 = 0.f, a1 = 0.f, a2 = 0.f, a3 = 0.f;
    float c0 = 0.f, c1 = 0.f, c2 = 0.f, c3 = 0.f;
    int i = s;
    for (; i + 4 <= e; i += 4) {
        int2 p0 = ew[i], p1 = ew[i + 1], p2 = ew[i + 2], p3 = ew[i + 3];
        u32 u0 = *(const u32*)(hin + (size_t)p0.x * EMBED + d2);
        u32 u1 = *(const u32*)(hin + (size_t)p1.x * EMBED + d2);
        u32 u2 = *(const u32*)(hin + (size_t)p2.x * EMBED + d2);
        u32 u3 = *(const u32*)(hin + (size_t)p3.x * EMBED + d2);
        float w0 = __int_as_float(p0.y), w1 = __int_as_float(p1.y);
        float w2 = __int_as_float(p2.y), w3 = __int_as_float(p3.y);
        a0 += w0 * bflo(u0); c0 += w0 * bfhi(u0);
        a1 += w1 * bflo(u1); c1 += w1 * bfhi(u1);
        a2 += w2 * bflo(u2); c2 += w2 * bfhi(u2);
        a3 += w3 * bflo(u3); c3 += w3 * bfhi(u3);
    }
    for (; i < e; ++i) {
        int2 p = ew[i];
        u32 u = *(const u32*)(hin + (size_t)p.x * EMBED + d2);
        float ww = __int_as_float(p.y);
        a0 += ww * bflo(u); c0 += ww * bfhi(u);
    }
    float dv = dinv[v];
    u32 us = *(const u32*)(hin + (size_t)v * EMBED + d2);
    u32 ux = *(const u32*)(x0 + (size_t)v * EMBED + d2);
    float accL = ((a0 + a1) + (a2 + a3)) + dv * dv * bflo(us);
    float accH = ((c0 + c1) + (c2 + c3)) + dv * dv * bfhi(us);
    float hL = 0.9f * accL + 0.1f * bflo(ux);
    float hH = 0.9f * accH + 0.1f * bfhi(ux);
    if (final_step) {
        *(float2*)(hof + (size_t)v * EMBED + d2) = make_float2(hL, hH);
    } else {
        u32 o = (u32)f2bf(hL) | ((u32)f2bf(hH) << 16);
        *(u32*)(hob + (size_t)v * EMBED + d2) = o;
    }
}

extern "C" void kernel_launch(void* const* d_in, const int* in_sizes, int n_in,
                              void* d_out, int out_size, void* d_ws, size_t ws_size,
                              hipStream_t stream)
{
    const float* x  = (const float*)d_in[0];
    const int*   ei = (const int*)d_in[1];
    const float* W1 = (const float*)d_in[2];
    const float* b1 = (const float*)d_in[3];
    const float* W2 = (const float*)d_in[4];
    const float* b2 = (const float*)d_in[5];
    float* out = (float*)d_out;
    const int* row = ei;
    const int* col = ei + N_EDGES;

    // workspace carve-out (~52 MB), all 16B-aligned
    char* w = (char*)d_ws;
    unsigned short* h0bf = (unsigned short*)w; w += (size_t)N_NODES * EMBED * 2;  // x0 (bf16)
    unsigned short* hbA  = (unsigned short*)w; w += (size_t)N_NODES * EMBED * 2;
    unsigned short* hbB  = (unsigned short*)w; w += (size_t)N_NODES * EMBED * 2;
    int*   cnt  = (int*)w;  w += (size_t)N_NODES * 4;
    int*   off  = (int*)w;  w += (size_t)(N_NODES + 1) * 4 + 12;
    int*   bsum = (int*)w;  w += 4096;
    float* dinv = (float*)w; w += (size_t)N_NODES * 4;
    int2*  ew   = (int2*)w;  w += (size_t)N_EDGES * 8;
    unsigned short* W1T = (unsigned short*)w; w += (size_t)IN_DIM * HIDDEN * 2;
    unsigned short* W2T = (unsigned short*)w; w += (size_t)HIDDEN * EMBED * 2;

    int nbN = (N_NODES + 255) / 256;
    int nbE = (N_EDGES + 255) / 256;

    conv_weights<<<(IN_DIM * HIDDEN + HIDDEN * EMBED + 255) / 256, 256, 0, stream>>>(W1, W2, W1T, W2T);
    mlp_mfma<<<(N_NODES + 63) / 64, 256, 0, stream>>>(x, W1T, b1, W2T, b2, h0bf, N_NODES);

    zero_int<<<nbN, 256, 0, stream>>>(cnt, N_NODES);
    count_deg<<<nbE, 256, 0, stream>>>(col, cnt, N_EDGES);
    calc_dinv<<<nbN, 256, 0, stream>>>(cnt, dinv, N_NODES);
    block_reduce<<<nbN, 256, 0, stream>>>(cnt, bsum, N_NODES);
    scan_bsum<<<1, 64, 0, stream>>>(bsum, nbN);
    block_scan<<<nbN, 256, 0, stream>>>(cnt, bsum, off, N_NODES);
    set_tail<<<1, 1, 0, stream>>>(off);
    fill_csc<<<nbE, 256, 0, stream>>>(row, col, off, cnt, dinv, ew, N_EDGES);

    // K=10 steps: step s<9 writes bf16 ping-pong, step 9 writes fp32 d_out
    const unsigned short* hin = h0bf;
    for (int s = 0; s < K_STEPS; ++s) {
        int fin = (s == K_STEPS - 1);
        unsigned short* hob = (s & 1) ? hbB : hbA;
        prop_bf16<<<N_NODES / 8, 256, 0, stream>>>(off, ew, hin, h0bf, dinv,
                                                   hob, out, fin);
        hin = hob;
    }
}